// Round 12
// baseline (106.271 us; speedup 1.0000x reference)
//
#include <hip/hip_runtime.h>
#include <hip/hip_bf16.h>

typedef __bf16 bf16;
typedef __attribute__((ext_vector_type(8))) __bf16 bf16x8;
typedef __attribute__((ext_vector_type(4))) __bf16 bf16x4;
typedef __attribute__((ext_vector_type(4))) float f32x4;
typedef __attribute__((ext_vector_type(4))) int i32x4;
typedef __attribute__((ext_vector_type(2))) int i32x2;

#define CH 192
#define MAT (CH * CH)            // 36864
#define NF 145                   // canonical frequencies of 17x17 grid (conj symmetry)
#define NELEM (CH * CH * 9)      // 331776
#define XSCALE 9.765625e-4f      // 2^-10, exact; sigma = 1024*(s3/289)^(1/16)
#define W17 0.36959913571644626f // 2*pi/17

// ---------------------------------------------------------------------------
// sigma = ||G^3(K)||_F^(1/8) via 17x17 spectral sampling (exact Parseval).
// ROUND-17 CHANGE (wait-event compression): r10(16w) and r11(8w) both landed
// at ~52us -> structure-insensitive floor = per-iteration WAIT EVENTS, not
// registers/occupancy. Old inner loop: 4 read-batches (A + B per nt) => ~24
// lgkmcnt waits/round/wave, lockstep waves contend instead of covering.
// New: per ks8 read ALL 18 frags (A12 + B6) upfront + pre-negate nbr ->
// ONE wait -> ONE 72-MFMA burst (nt-outer/mt-inner per product group; dep
// distance per accum 18+). Per-accumulator op order UNCHANGED (cr: +ar*br,
// +ai*bi; ci: +ar*bi, +ai*nbr) -> bitwise identical. Waits/round: 24 -> 6.
// Regs: 144 acc + 84 frag + ~12 addr ~= 240 <= 256 (2 waves/SIMD). Dropped
// s_setprio (null in lockstep, m190).
// Lessons pinned:
//  - r10/r11: 16w vs 8w vs staging variants all ~52us -> bottleneck is wait
//    events / burst granularity, not occupancy or reg budget.
//  - ci Hermitian mirror NOT bitwise (r9). cr is. No mirrors.
//  - Lane-adjacent addresses must be contiguous (r7 gather +22us).
//  - XOR chunk swizzle c'=(c&~7)|((c&7)^(r&7)) BOTH sides: conflicts 2M->0.
//  - FETCH ~9MB = Kt x8 XCDs; WRITE ~8MB = harness-fill dirty-L2 writeback.
//    WRITE balloon = spill tell -> revert.
//  - harness ws fill (~44 us) is inside the timed window: floor = 44 + work.
// ws layout: [0] float s3; [256] Kt f32 [i][a][o] 9 planes (1.33 MB).
// ---------------------------------------------------------------------------

__device__ __forceinline__ int swz8(int c, int r) {
    return (c & ~7) | ((c & 7) ^ (r & 7));       // 16-B chunk XOR swizzle
}

// Kt[i*MAT + a*CH + o] = K[(o*CH+a)*9 + i]; coalesced 36-B read per thread,
// 9 scattered scalar writes (fire-and-forget). Also zeroes s3.
__global__ void k_tr(const float* __restrict__ K, float* __restrict__ Kt,
                     float* __restrict__ s3) {
    int p = blockIdx.x * 256 + threadIdx.x;      // 144 blocks = 36864 rows
    if (p == 0) *s3 = 0.0f;
    int o = p / CH, a = p % CH;
    const float* src = K + (size_t)p * 9;
#pragma unroll
    for (int i = 0; i < 9; ++i)
        Kt[(size_t)i * MAT + a * CH + o] = src[i];
}

// ---------------------------------------------------------------------------
// k_g3: per-frequency fused DFT + triple gram. One block = one freq, 512 thr.
// Staging: 9-plane coeff DFT, coalesced f32x4 plane reads -> swizzled LDS
// (Re/Im slabs [192][192] bf16, 147456 B). Rounds: 8 waves, wave w owns a
// 96x48 tile; per ks8: 18-read batch -> 72-MFMA burst -> barrier ->
// transposed-packed b64 write-back -> barrier. Round 3: skip fully-below
// tiles; per-element-weighted Frobenius norm -> atomic.
// ---------------------------------------------------------------------------
__global__ __launch_bounds__(512, 2)
__attribute__((amdgpu_waves_per_eu(2, 2)))
void k_g3(const float* __restrict__ Kt, float* __restrict__ s3) {
    __shared__ __align__(16) bf16 lds[2 * MAT];   // 147456 B
    __shared__ float twc[17], tws[17];
    __shared__ float red[8];
    int f = blockIdx.x;                 // 145 blocks
    int tid = threadIdx.x;
    int lane = tid & 63, w = tid >> 6;
    int ml = lane & 15, kqc = lane >> 4;
    int mlb = ml & 7;                   // swizzle row-bit (bands are 0 mod 16)
    int rb = (w >> 2) * 96;             // 2 row bands (96 rows each)
    int cb = (w & 3) * 48;              // 4 col bands (48 cols each)
    // round 3: tiles fully below the diagonal contribute nothing
    bool comp3 = !(rb == 96 && cb < 96);   // skip waves 4,5

    if (tid < 17) {
        float s, c;
        __sincosf(-W17 * (float)tid, &s, &c);
        twc[tid] = c; tws[tid] = s;
    }
    __syncthreads();

    // ---- 9 block-uniform complex coeffs c[y*3+x] = py^y * px^x * 2^-10 ----
    int fy, fx;
    if (f < 9) { fy = 0; fx = f; }
    else { int uu = f - 9; fy = 1 + uu / 17; fx = uu % 17; }
    float pyr = twc[fy], pyi = tws[fy];
    float pxr = twc[fx], pxi = tws[fx];
    int fx2 = 2 * fx; if (fx2 >= 17) fx2 -= 17;
    int fy2 = 2 * fy; if (fy2 >= 17) fy2 -= 17;
    float px2r = twc[fx2], px2i = tws[fx2];
    float py2r = twc[fy2], py2i = tws[fy2];
    float cR[9], cI[9];
    cR[0] = 1.0f;  cI[0] = 0.0f;
    cR[1] = pxr;   cI[1] = pxi;
    cR[2] = px2r;  cI[2] = px2i;
    cR[3] = pyr;   cI[3] = pyi;
    cR[4] = pyr * pxr - pyi * pxi;    cI[4] = pyr * pxi + pyi * pxr;
    cR[5] = pyr * px2r - pyi * px2i;  cI[5] = pyr * px2i + pyi * px2r;
    cR[6] = py2r;  cI[6] = py2i;
    cR[7] = py2r * pxr - py2i * pxi;  cI[7] = py2r * pxi + py2i * pxr;
    cR[8] = py2r * px2r - py2i * px2i; cI[8] = py2r * px2i + py2i * px2r;
#pragma unroll
    for (int i = 0; i < 9; ++i) { cR[i] *= XSCALE; cI[i] *= XSCALE; }  // exact 2^-10

    // ---- stage: X_f = sum_i c_i * plane_i -> swizzled LDS (4608 chunks) ----
#pragma unroll 1
    for (int j = 0; j < 9; ++j) {                 // 9 x 512 = 4608 exact
        int cidx = j * 512 + tid;
        int a = cidx / 24, c = cidx % 24;
        const float* base = Kt + a * CH + c * 8;
        float xr0 = 0.f, xr1 = 0.f, xr2 = 0.f, xr3 = 0.f;
        float xr4 = 0.f, xr5 = 0.f, xr6 = 0.f, xr7 = 0.f;
        float xi0 = 0.f, xi1 = 0.f, xi2 = 0.f, xi3 = 0.f;
        float xi4 = 0.f, xi5 = 0.f, xi6 = 0.f, xi7 = 0.f;
#pragma unroll
        for (int i = 0; i < 9; ++i) {
            f32x4 lo = *(const f32x4*)(base + (size_t)i * MAT);
            f32x4 hi = *(const f32x4*)(base + (size_t)i * MAT + 4);
            float r = cR[i], m = cI[i];
            xr0 += r * lo[0]; xi0 += m * lo[0];
            xr1 += r * lo[1]; xi1 += m * lo[1];
            xr2 += r * lo[2]; xi2 += m * lo[2];
            xr3 += r * lo[3]; xi3 += m * lo[3];
            xr4 += r * hi[0]; xi4 += m * hi[0];
            xr5 += r * hi[1]; xi5 += m * hi[1];
            xr6 += r * hi[2]; xi6 += m * hi[2];
            xr7 += r * hi[3]; xi7 += m * hi[3];
        }
        bf16x8 vr, vi;
        vr[0] = (bf16)xr0; vr[1] = (bf16)xr1; vr[2] = (bf16)xr2; vr[3] = (bf16)xr3;
        vr[4] = (bf16)xr4; vr[5] = (bf16)xr5; vr[6] = (bf16)xr6; vr[7] = (bf16)xr7;
        vi[0] = (bf16)xi0; vi[1] = (bf16)xi1; vi[2] = (bf16)xi2; vi[3] = (bf16)xi3;
        vi[4] = (bf16)xi4; vi[5] = (bf16)xi5; vi[6] = (bf16)xi6; vi[7] = (bf16)xi7;
        int e = a * CH + swz8(c, a) * 8;          // swizzled (write side)
        *(i32x4*)&lds[e]       = __builtin_bit_cast(i32x4, vr);
        *(i32x4*)&lds[MAT + e] = __builtin_bit_cast(i32x4, vi);
    }
    __syncthreads();

    // per-thread frag row constants
    int arow[6], brow[3];
#pragma unroll
    for (int i = 0; i < 6; ++i) arow[i] = (rb + i * 16 + ml) * CH;
#pragma unroll
    for (int i = 0; i < 3; ++i) brow[i] = (cb + i * 16 + ml) * CH;

    f32x4 cr[6][3], ci[6][3];
#pragma unroll 1
    for (int round = 0; round < 3; ++round) {
        bool active = (round < 2) || comp3;
#pragma unroll
        for (int i = 0; i < 6; ++i)
#pragma unroll
            for (int j = 0; j < 3; ++j) {
                cr[i][j] = f32x4{0.f, 0.f, 0.f, 0.f};
                ci[i][j] = f32x4{0.f, 0.f, 0.f, 0.f};
            }
        if (active) {
#pragma unroll
            for (int t = 0; t < 6; ++t) {               // K step 32 = 4 chunks
                int sw = swz8(t * 4 + kqc, mlb) * 8;
                // ---- 18-read batch: A(12) + B(6); ONE wait ----
                bf16x8 ar[6], ai[6], br[3], bi[3], nbr[3];
#pragma unroll
                for (int mt = 0; mt < 6; ++mt) {
                    int e = arow[mt] + sw;
                    ar[mt] = *(const bf16x8*)&lds[e];
                    ai[mt] = *(const bf16x8*)&lds[MAT + e];
                }
#pragma unroll
                for (int nt = 0; nt < 3; ++nt) {
                    int e = brow[nt] + sw;
                    br[nt] = *(const bf16x8*)&lds[e];
                    bi[nt] = *(const bf16x8*)&lds[MAT + e];
                    i32x4 u = __builtin_bit_cast(i32x4, br[nt]);
                    u ^= 0x80008000;                    // nbr = -br (8 bf16)
                    nbr[nt] = __builtin_bit_cast(bf16x8, u);
                }
                // ---- 72-MFMA burst; per-accumulator order unchanged:
                // cr: +ar*br then +ai*bi ; ci: +ar*bi then +ai*nbr ----
#pragma unroll
                for (int nt = 0; nt < 3; ++nt)
#pragma unroll
                    for (int mt = 0; mt < 6; ++mt)
                        cr[mt][nt] = __builtin_amdgcn_mfma_f32_16x16x32_bf16(ar[mt], br[nt],  cr[mt][nt], 0, 0, 0);
#pragma unroll
                for (int nt = 0; nt < 3; ++nt)
#pragma unroll
                    for (int mt = 0; mt < 6; ++mt)
                        ci[mt][nt] = __builtin_amdgcn_mfma_f32_16x16x32_bf16(ar[mt], bi[nt],  ci[mt][nt], 0, 0, 0);
#pragma unroll
                for (int nt = 0; nt < 3; ++nt)
#pragma unroll
                    for (int mt = 0; mt < 6; ++mt)
                        cr[mt][nt] = __builtin_amdgcn_mfma_f32_16x16x32_bf16(ai[mt], bi[nt],  cr[mt][nt], 0, 0, 0);
#pragma unroll
                for (int nt = 0; nt < 3; ++nt)
#pragma unroll
                    for (int mt = 0; mt < 6; ++mt)
                        ci[mt][nt] = __builtin_amdgcn_mfma_f32_16x16x32_bf16(ai[mt], nbr[nt], ci[mt][nt], 0, 0, 0);
            }
        }
        if (round < 2) {
            __syncthreads();                        // all LDS reads done
            // transposed-packed write-back: store H^T (bitwise-Hermitian ->
            // transposes cancel across rounds). Lane's 4 rr rows are 4
            // consecutive elems of the stored column -> one b64 per plane.
            int lrq = kqc * 4;
#pragma unroll
            for (int mt = 0; mt < 6; ++mt) {
                int row0 = rb + mt * 16 + lrq;      // multiple of 4
                int rc = row0 >> 3, rlo = row0 & 7; // rlo in {0,4}
#pragma unroll
                for (int nt = 0; nt < 3; ++nt) {
                    int col = cb + nt * 16 + ml;
                    int e = col * CH + swz8(rc, mlb) * 8 + rlo;  // col&7 == mlb
                    bf16x4 pr, pi;
#pragma unroll
                    for (int rr = 0; rr < 4; ++rr) {
                        pr[rr] = (bf16)cr[mt][nt][rr];
                        pi[rr] = (bf16)ci[mt][nt][rr];
                    }
                    *(i32x2*)&lds[e]       = __builtin_bit_cast(i32x2, pr);
                    *(i32x2*)&lds[MAT + e] = __builtin_bit_cast(i32x2, pi);
                }
            }
            __syncthreads();                        // writes visible to round+1
        }
    }

    // ---- norm of round-3 accums: per-element weight 2/1/0 (above/diag/
    // below); computed tiles cover the upper triangle exactly once ----
    float loc = 0.f;
#pragma unroll
    for (int mt = 0; mt < 6; ++mt)
#pragma unroll
        for (int nt = 0; nt < 3; ++nt)
#pragma unroll
            for (int rr = 0; rr < 4; ++rr) {
                int row = rb + mt * 16 + kqc * 4 + rr;
                int col = cb + nt * 16 + ml;
                float wt = (col > row) ? 2.0f : ((col == row) ? 1.0f : 0.0f);
                loc += wt * (cr[mt][nt][rr] * cr[mt][nt][rr] +
                             ci[mt][nt][rr] * ci[mt][nt][rr]);
            }
#pragma unroll
    for (int off = 32; off > 0; off >>= 1) loc += __shfl_down(loc, off, 64);
    if (lane == 0) red[w] = loc;
    __syncthreads();
    if (tid == 0) {
        float base = (f == 0) ? 1.0f : 2.0f;        // conj-pair weight over freqs
        float acc = 0.f;
#pragma unroll
        for (int i = 0; i < 8; ++i) acc += red[i];
        atomicAdd(s3, base * acc);
    }
}

// sigma = 1024 * (s3/289)^(1/16);  out = K / sigma
__global__ void k_scale(const float* __restrict__ K, float* __restrict__ out,
                        const float* __restrict__ s3) {
    float sig = 1024.0f * exp2f(log2f((*s3) * (1.0f / 289.0f)) * 0.0625f);
    float inv = 1.0f / sig;
    int i = (blockIdx.x * 256 + threadIdx.x) * 4;   // 324 blocks exact
    f32x4 v = *(const f32x4*)(K + i);
    v *= inv;
    *(f32x4*)(out + i) = v;
}

extern "C" void kernel_launch(void* const* d_in, const int* in_sizes, int n_in,
                              void* d_out, int out_size, void* d_ws, size_t ws_size,
                              hipStream_t stream) {
    const float* K = (const float*)d_in[0];
    float* out = (float*)d_out;
    char* ws = (char*)d_ws;
    float* s3 = (float*)ws;
    float* Kt = (float*)(ws + 256);

    k_tr<<<NELEM / (256 * 9), 256, 0, stream>>>(K, Kt, s3);   // 9-plane Kt + s3=0
    k_g3<<<NF, 512, 0, stream>>>(Kt, s3);                     // DFT + 3 gram rounds
    k_scale<<<NELEM / 1024, 256, 0, stream>>>(K, out, s3);    // out = K/sigma
}

// Round 14
// 98.960 us; speedup vs baseline: 1.0739x; 1.0739x over previous
//
#include <hip/hip_runtime.h>
#include <hip/hip_bf16.h>

typedef __bf16 bf16;
typedef __attribute__((ext_vector_type(8))) __bf16 bf16x8;
typedef __attribute__((ext_vector_type(4))) __bf16 bf16x4;
typedef __attribute__((ext_vector_type(4))) float f32x4;
typedef __attribute__((ext_vector_type(4))) int i32x4;
typedef __attribute__((ext_vector_type(2))) int i32x2;

#define CH 192
#define MAT (CH * CH)            // 36864
#define NF 145                   // canonical frequencies of 17x17 grid (conj symmetry)
#define NELEM (CH * CH * 9)      // 331776
#define XSCALE 9.765625e-4f      // 2^-10, exact; sigma = 1024*(s3/289)^(1/16)
#define W17 0.36959913571644626f // 2*pi/17

// ---------------------------------------------------------------------------
// sigma = ||G^3(K)||_F^(1/8) via 17x17 spectral sampling (exact Parseval).
// ROUND-19: RESUBMIT of round-18 (container infra failure, no data). A/B on
// the best-measured config (r10 16-wave kernel, total 103.66us, k_g3
// 52.4us): REMOVE s_setprio only (m190: setprio slightly negative on
// barrier-lockstep structures; it was bundled in r10, never isolated).
// Everything else bit-identical to r10.
// WALL EVIDENCE (5 variants, k_g3 52-54us): r5 global-X staging 52;
// r10 16-wave 48x48 52.4; r11 8-wave 96x48 per-nt 52.9; r12 8-wave
// 18-frag mega-burst 54.2 (slight spill, WRITE 8.1->12.8MB); r9 triangle
// mirror FAILED numerics. Corrected MFMA model: 19.4 cyc/MFMA/SIMD (m06)
// -> rounds floor 21us + staging 4 + WB 3 = 28us ideal vs 52 measured;
// residual is in-loop LDS-latency stall, invariant to 2 vs 4 waves/SIMD,
// burst size, and batch width. Next big lever (Hermitian triangle,
// -37.5% MFMA) is numerics-blocked (r9: ci mirror half-sum order swap;
// ci1/ci2 split needs unverifiable HW k-order uniformity + 216 accums).
// Lessons pinned:
//  - ci Hermitian mirror NOT bitwise (r9). cr is. No mirrors.
//  - 16-wave block: ~64 arch VGPR; accums in unified file. 8-wave: 128.
//    Exceeding either spills (WRITE_SIZE is the tell).
//  - Lane-adjacent addresses must be contiguous (r7 gather +22us).
//  - XOR chunk swizzle c'=(c&~7)|((c&7)^(r&7)) BOTH sides: conflicts 2M->0.
//  - FETCH ~9MB = Kt x8 XCDs; WRITE ~8MB = harness-fill dirty-L2 writeback.
//  - harness ws fill (~44 us) is inside the timed window: floor = 44 + work.
// ws layout: [0] float s3; [256] Kt f32 [i][a][o] 9 planes (1.33 MB).
// ---------------------------------------------------------------------------

__device__ __forceinline__ int swz8(int c, int r) {
    return (c & ~7) | ((c & 7) ^ (r & 7));       // 16-B chunk XOR swizzle
}

// Kt[i*MAT + a*CH + o] = K[(o*CH+a)*9 + i]; coalesced 36-B read per thread,
// 9 scattered scalar writes (fire-and-forget). Also zeroes s3.
__global__ void k_tr(const float* __restrict__ K, float* __restrict__ Kt,
                     float* __restrict__ s3) {
    int p = blockIdx.x * 256 + threadIdx.x;      // 144 blocks = 36864 rows
    if (p == 0) *s3 = 0.0f;
    int o = p / CH, a = p % CH;
    const float* src = K + (size_t)p * 9;
#pragma unroll
    for (int i = 0; i < 9; ++i)
        Kt[(size_t)i * MAT + a * CH + o] = src[i];
}

// ---------------------------------------------------------------------------
// k_g3: per-frequency fused DFT + triple gram. One block = one freq, 1024 thr.
// Staging: 9-plane coeff DFT, coalesced f32x4 plane reads -> swizzled LDS
// (Re/Im slabs [192][192] bf16, 147456 B). Rounds 1-2: full 16 tiles (wave w
// = rows (w>>2)*48, cols (w&3)*48); MFMA mt-major -> barrier -> transposed-
// packed b64 write-back -> barrier. Round 3: balanced 10-tile triangle
// (waves 0-9), norm of accums (off-diag x2) -> atomic.
// ---------------------------------------------------------------------------
__global__ __launch_bounds__(1024, 4)
__attribute__((amdgpu_waves_per_eu(4, 4)))
void k_g3(const float* __restrict__ Kt, float* __restrict__ s3) {
    __shared__ __align__(16) bf16 lds[2 * MAT];   // 147456 B
    __shared__ float twc[17], tws[17];
    __shared__ float red[16];
    int f = blockIdx.x;                 // 145 blocks
    int tid = threadIdx.x;
    int lane = tid & 63, w = tid >> 6;
    int ml = lane & 15, kqc = lane >> 4;
    int mlb = ml & 7;                   // swizzle row-bit for ALL frag rows
    int rb = (w >> 2) * 48;             // rounds 1-2: full 4x4 tiling
    int cb = (w & 3) * 48;
    // round-3 balanced triangle: waves 0-9 -> (0,0)(0,1)(0,2)(0,3)(1,1)
    // (1,2)(1,3)(2,2)(2,3)(3,3); per-SIMD active = 3,3,2,2
    int tr = (w >= 4) + (w >= 7) + (w >= 9);
    int tbase = (tr == 0) ? 0 : (tr == 1) ? 4 : (tr == 2) ? 7 : 9;
    int tc = w - tbase + tr;
    bool comp3 = (w < 10);
    bool offd3 = comp3 && (tc > tr);
    int rb3 = tr * 48, cb3 = tc * 48;

    if (tid < 17) {
        float s, c;
        __sincosf(-W17 * (float)tid, &s, &c);
        twc[tid] = c; tws[tid] = s;
    }
    __syncthreads();

    // ---- 9 block-uniform complex coeffs c[y*3+x] = py^y * px^x * 2^-10 ----
    int fy, fx;
    if (f < 9) { fy = 0; fx = f; }
    else { int uu = f - 9; fy = 1 + uu / 17; fx = uu % 17; }
    float pyr = twc[fy], pyi = tws[fy];
    float pxr = twc[fx], pxi = tws[fx];
    int fx2 = 2 * fx; if (fx2 >= 17) fx2 -= 17;
    int fy2 = 2 * fy; if (fy2 >= 17) fy2 -= 17;
    float px2r = twc[fx2], px2i = tws[fx2];
    float py2r = twc[fy2], py2i = tws[fy2];
    float cR[9], cI[9];
    cR[0] = 1.0f;  cI[0] = 0.0f;
    cR[1] = pxr;   cI[1] = pxi;
    cR[2] = px2r;  cI[2] = px2i;
    cR[3] = pyr;   cI[3] = pyi;
    cR[4] = pyr * pxr - pyi * pxi;    cI[4] = pyr * pxi + pyi * pxr;
    cR[5] = pyr * px2r - pyi * px2i;  cI[5] = pyr * px2i + pyi * px2r;
    cR[6] = py2r;  cI[6] = py2i;
    cR[7] = py2r * pxr - py2i * pxi;  cI[7] = py2r * pxi + py2i * pxr;
    cR[8] = py2r * px2r - py2i * px2i; cI[8] = py2r * px2i + py2i * px2r;
#pragma unroll
    for (int i = 0; i < 9; ++i) { cR[i] *= XSCALE; cI[i] *= XSCALE; }  // exact 2^-10

    // ---- stage: X_f = sum_i c_i * plane_i -> swizzled LDS (4608 chunks) ----
#pragma unroll 1
    for (int j5 = 0; j5 < 5; ++j5) {
        int cidx = j5 * 1024 + tid;
        if (cidx < 4608) {                        // last pass: waves 0-7 only
            int a = cidx / 24, c = cidx % 24;
            const float* base = Kt + a * CH + c * 8;
            float xr0 = 0.f, xr1 = 0.f, xr2 = 0.f, xr3 = 0.f;
            float xr4 = 0.f, xr5 = 0.f, xr6 = 0.f, xr7 = 0.f;
            float xi0 = 0.f, xi1 = 0.f, xi2 = 0.f, xi3 = 0.f;
            float xi4 = 0.f, xi5 = 0.f, xi6 = 0.f, xi7 = 0.f;
#pragma unroll
            for (int i = 0; i < 9; ++i) {
                f32x4 lo = *(const f32x4*)(base + (size_t)i * MAT);
                f32x4 hi = *(const f32x4*)(base + (size_t)i * MAT + 4);
                float r = cR[i], m = cI[i];
                xr0 += r * lo[0]; xi0 += m * lo[0];
                xr1 += r * lo[1]; xi1 += m * lo[1];
                xr2 += r * lo[2]; xi2 += m * lo[2];
                xr3 += r * lo[3]; xi3 += m * lo[3];
                xr4 += r * hi[0]; xi4 += m * hi[0];
                xr5 += r * hi[1]; xi5 += m * hi[1];
                xr6 += r * hi[2]; xi6 += m * hi[2];
                xr7 += r * hi[3]; xi7 += m * hi[3];
            }
            bf16x8 vr, vi;
            vr[0] = (bf16)xr0; vr[1] = (bf16)xr1; vr[2] = (bf16)xr2; vr[3] = (bf16)xr3;
            vr[4] = (bf16)xr4; vr[5] = (bf16)xr5; vr[6] = (bf16)xr6; vr[7] = (bf16)xr7;
            vi[0] = (bf16)xi0; vi[1] = (bf16)xi1; vi[2] = (bf16)xi2; vi[3] = (bf16)xi3;
            vi[4] = (bf16)xi4; vi[5] = (bf16)xi5; vi[6] = (bf16)xi6; vi[7] = (bf16)xi7;
            int e = a * CH + swz8(c, a) * 8;      // swizzled (write side)
            *(i32x4*)&lds[e]       = __builtin_bit_cast(i32x4, vr);
            *(i32x4*)&lds[MAT + e] = __builtin_bit_cast(i32x4, vi);
        }
    }
    __syncthreads();

    f32x4 cr[3][3], ci[3][3];
#pragma unroll 1
    for (int round = 0; round < 3; ++round) {
        bool last = (round == 2);
        int Rb = last ? rb3 : rb;
        int Cb = last ? cb3 : cb;
        bool active = !last || comp3;
#pragma unroll
        for (int i = 0; i < 3; ++i)
#pragma unroll
            for (int j = 0; j < 3; ++j) {
                cr[i][j] = f32x4{0.f, 0.f, 0.f, 0.f};
                ci[i][j] = f32x4{0.f, 0.f, 0.f, 0.f};
            }
        if (active) {
#pragma unroll
            for (int ks8 = 0; ks8 < 24; ks8 += 4) {     // K step 32 = 4 chunks
                int c0 = ks8 + kqc;
                int sw = swz8(c0, mlb) * 8;             // same for all frag rows
                bf16x8 ar[3], ai[3];
#pragma unroll
                for (int mt = 0; mt < 3; ++mt) {
                    int e = (Rb + mt * 16 + ml) * CH + sw;
                    ar[mt] = *(const bf16x8*)&lds[e];
                    ai[mt] = *(const bf16x8*)&lds[MAT + e];
                }
#pragma unroll
                for (int nt = 0; nt < 3; ++nt) {
                    int e = (Cb + nt * 16 + ml) * CH + sw;
                    bf16x8 br = *(const bf16x8*)&lds[e];
                    bf16x8 bi = *(const bf16x8*)&lds[MAT + e];
                    i32x4 u = __builtin_bit_cast(i32x4, br);
                    u ^= 0x80008000;                    // nbr = -br (8 bf16)
                    bf16x8 nbr = __builtin_bit_cast(bf16x8, u);
                    // mt-major: per-accumulator order unchanged; dep dist 6
#pragma unroll
                    for (int mt = 0; mt < 3; ++mt)
                        cr[mt][nt] = __builtin_amdgcn_mfma_f32_16x16x32_bf16(ar[mt], br,  cr[mt][nt], 0, 0, 0);
#pragma unroll
                    for (int mt = 0; mt < 3; ++mt)
                        ci[mt][nt] = __builtin_amdgcn_mfma_f32_16x16x32_bf16(ar[mt], bi,  ci[mt][nt], 0, 0, 0);
#pragma unroll
                    for (int mt = 0; mt < 3; ++mt)
                        cr[mt][nt] = __builtin_amdgcn_mfma_f32_16x16x32_bf16(ai[mt], bi,  cr[mt][nt], 0, 0, 0);
#pragma unroll
                    for (int mt = 0; mt < 3; ++mt)
                        ci[mt][nt] = __builtin_amdgcn_mfma_f32_16x16x32_bf16(ai[mt], nbr, ci[mt][nt], 0, 0, 0);
                }
            }
        }
        if (!last) {
            __syncthreads();                        // all LDS reads done
            // transposed-packed write-back: store H^T (bitwise-Hermitian ->
            // transposes cancel across rounds; s3 unchanged). Lane's 4 rr
            // rows are 4 consecutive elems of stored column -> one b64.
            int lrq = kqc * 4;
#pragma unroll
            for (int mt = 0; mt < 3; ++mt) {
                int row0 = rb + mt * 16 + lrq;      // multiple of 4
                int rc = row0 >> 3, rlo = row0 & 7; // rlo in {0,4}
#pragma unroll
                for (int nt = 0; nt < 3; ++nt) {
                    int col = cb + nt * 16 + ml;
                    int e = col * CH + swz8(rc, mlb) * 8 + rlo;  // col&7 == mlb
                    bf16x4 pr, pi;
#pragma unroll
                    for (int rr = 0; rr < 4; ++rr) {
                        pr[rr] = (bf16)cr[mt][nt][rr];
                        pi[rr] = (bf16)ci[mt][nt][rr];
                    }
                    *(i32x2*)&lds[e]       = __builtin_bit_cast(i32x2, pr);
                    *(i32x2*)&lds[MAT + e] = __builtin_bit_cast(i32x2, pi);
                }
            }
            __syncthreads();                        // writes visible to round+1
        }
    }

    // ---- norm of round-3 accums: triangle, diag w=1, off-diag w=2 ----
    float loc = 0.f;
#pragma unroll
    for (int mt = 0; mt < 3; ++mt)
#pragma unroll
        for (int nt = 0; nt < 3; ++nt)
#pragma unroll
            for (int rr = 0; rr < 4; ++rr)
                loc += cr[mt][nt][rr] * cr[mt][nt][rr] + ci[mt][nt][rr] * ci[mt][nt][rr];
    loc *= offd3 ? 2.0f : (comp3 ? 1.0f : 0.0f);
#pragma unroll
    for (int off = 32; off > 0; off >>= 1) loc += __shfl_down(loc, off, 64);
    if (lane == 0) red[w] = loc;
    __syncthreads();
    if (tid == 0) {
        float base = (f == 0) ? 1.0f : 2.0f;        // conj-pair weight over freqs
        float acc = 0.f;
#pragma unroll
        for (int i = 0; i < 16; ++i) acc += red[i];
        atomicAdd(s3, base * acc);
    }
}

// sigma = 1024 * (s3/289)^(1/16);  out = K / sigma
__global__ void k_scale(const float* __restrict__ K, float* __restrict__ out,
                        const float* __restrict__ s3) {
    float sig = 1024.0f * exp2f(log2f((*s3) * (1.0f / 289.0f)) * 0.0625f);
    float inv = 1.0f / sig;
    int i = (blockIdx.x * 256 + threadIdx.x) * 4;   // 324 blocks exact
    f32x4 v = *(const f32x4*)(K + i);
    v *= inv;
    *(f32x4*)(out + i) = v;
}

extern "C" void kernel_launch(void* const* d_in, const int* in_sizes, int n_in,
                              void* d_out, int out_size, void* d_ws, size_t ws_size,
                              hipStream_t stream) {
    const float* K = (const float*)d_in[0];
    float* out = (float*)d_out;
    char* ws = (char*)d_ws;
    float* s3 = (float*)ws;
    float* Kt = (float*)(ws + 256);

    k_tr<<<NELEM / (256 * 9), 256, 0, stream>>>(K, Kt, s3);   // 9-plane Kt + s3=0
    k_g3<<<NF, 1024, 0, stream>>>(Kt, s3);                    // DFT + 3 gram rounds
    k_scale<<<NELEM / 1024, 256, 0, stream>>>(K, out, s3);    // out = K/sigma
}

// Round 15
// 97.165 us; speedup vs baseline: 1.0937x; 1.0185x over previous
//
#include <hip/hip_runtime.h>
#include <hip/hip_bf16.h>

typedef __bf16 bf16;
typedef __attribute__((ext_vector_type(8))) __bf16 bf16x8;
typedef __attribute__((ext_vector_type(4))) __bf16 bf16x4;
typedef __attribute__((ext_vector_type(4))) float f32x4;
typedef __attribute__((ext_vector_type(4))) int i32x4;
typedef __attribute__((ext_vector_type(2))) int i32x2;

#define CH 192
#define MAT (CH * CH)            // 36864
#define NF 145                   // canonical frequencies of 17x17 grid (conj symmetry)
#define NELEM (CH * CH * 9)      // 331776
#define XSCALE 9.765625e-4f      // 2^-10, exact; sigma = 1024*(s3/289)^(1/16)
#define W17 0.36959913571644626f // 2*pi/17

// ---------------------------------------------------------------------------
// sigma = ||G^3(K)||_F^(1/8) via 17x17 spectral sampling (exact Parseval).
// ROUND-20 CHANGE (register headroom for pipelining): r14 proved setprio was
// costing 9us (52.4 -> 43.3 after removal; m190 understated it; the r10-r12
// "structure-invariant wall" was partly the setprio confound). Remaining gap
// 43.3 vs ~28us ideal = in-loop lgkmcnt stalls; at 16 waves the 128-reg/wave
// budget left ~0 spare regs to hoist next-iteration ds_reads. This round:
//  - 12 waves (768 thr), 48x64 tile/wave (rb=(w/3)*48, cb=(w%3)*64),
//    waves_per_eu(3,3) -> 170 regs/wave. Live: 96 acc + 24 A + 12 B + addr
//    ~= 147 -> ~23 SPARE regs for compiler software-pipelining; still
//    3 waves/SIMD latency coverage.
//  - staging: 6 x 768 = 4608 chunks EXACT.
//  - round 3: 9-tile balanced triangle (packed-const wave->tile map,
//    3,2,2,2 active/SIMD), per-element 2/1/0 weights.
// BITWISE: per-entry MFMA k-order and bf16 conversion points identical to
// r14; only wave->tile map + s3 reduction grouping change (absmax stayed
// exactly 2.441406e-4 under the same remap class in r10/r14).
// Lessons pinned:
//  - s_setprio around MFMA in barrier-lockstep blocks: -17% (r14). NEVER.
//  - ci Hermitian mirror NOT bitwise (r9). cr is. No mirrors.
//  - Per-wave reg budget = 512/(waves per SIMD). Exceed -> spill
//    (WRITE_SIZE is the tell).
//  - Lane-adjacent addresses must be contiguous (r7 gather +22us).
//  - XOR chunk swizzle c'=(c&~7)|((c&7)^(r&7)) BOTH sides: conflicts 2M->0.
//  - FETCH ~6MB = Kt x XCD replicas; WRITE ~4MB = harness dirty-L2
//    writeback, NOT scratch.
//  - harness ws fill (~44 us) is inside the timed window: floor = 44 + work.
// ws layout: [0] float s3; [256] Kt f32 [i][a][o] 9 planes (1.33 MB).
// ---------------------------------------------------------------------------

__device__ __forceinline__ int swz8(int c, int r) {
    return (c & ~7) | ((c & 7) ^ (r & 7));       // 16-B chunk XOR swizzle
}

// Kt[i*MAT + a*CH + o] = K[(o*CH+a)*9 + i]; coalesced 36-B read per thread,
// 9 scattered scalar writes (fire-and-forget). Also zeroes s3.
__global__ void k_tr(const float* __restrict__ K, float* __restrict__ Kt,
                     float* __restrict__ s3) {
    int p = blockIdx.x * 256 + threadIdx.x;      // 144 blocks = 36864 rows
    if (p == 0) *s3 = 0.0f;
    int o = p / CH, a = p % CH;
    const float* src = K + (size_t)p * 9;
#pragma unroll
    for (int i = 0; i < 9; ++i)
        Kt[(size_t)i * MAT + a * CH + o] = src[i];
}

// ---------------------------------------------------------------------------
// k_g3: per-frequency fused DFT + triple gram. One block = one freq, 768 thr.
// Staging: 9-plane coeff DFT, coalesced f32x4 plane reads -> swizzled LDS
// (Re/Im slabs [192][192] bf16, 147456 B). Rounds 1-2: 12 tiles of 48x64
// (wave w: rows (w/3)*48, cols (w%3)*64); MFMA mt-major -> barrier ->
// transposed-packed b64 write-back -> barrier. Round 3: balanced 9-tile
// triangle, per-element-weighted norm -> atomic.
// ---------------------------------------------------------------------------
__global__ __launch_bounds__(768, 3)
__attribute__((amdgpu_waves_per_eu(3, 3)))
void k_g3(const float* __restrict__ Kt, float* __restrict__ s3) {
    __shared__ __align__(16) bf16 lds[2 * MAT];   // 147456 B
    __shared__ float twc[17], tws[17];
    __shared__ float red[12];
    int f = blockIdx.x;                 // 145 blocks
    int tid = threadIdx.x;
    int lane = tid & 63, w = tid >> 6;  // 12 waves
    int ml = lane & 15, kqc = lane >> 4;
    int mlb = ml & 7;                   // swizzle row-bit (bands are 0 mod 16)
    int rb = (w / 3) * 48;              // rounds 1-2: 4x3 tiling, 48x64/wave
    int cb = (w % 3) * 64;
    // round-3 balanced triangle: 9 active tiles (skip fully-below (2,0),
    // (3,0),(3,1)); waves 0-8 -> tiles via packed consts; SIMD active 3,2,2,2
    bool comp3 = (w < 9);
    int tr3 = (0x3A540 >> (2 * w)) & 3;     // 0,0,0,1,1,1,2,2,3
    int tc3 = (0x29924 >> (2 * w)) & 3;     // 0,1,2,0,1,2,1,2,2
    int rb3 = tr3 * 48, cb3 = tc3 * 64;

    if (tid < 17) {
        float s, c;
        __sincosf(-W17 * (float)tid, &s, &c);
        twc[tid] = c; tws[tid] = s;
    }
    __syncthreads();

    // ---- 9 block-uniform complex coeffs c[y*3+x] = py^y * px^x * 2^-10 ----
    int fy, fx;
    if (f < 9) { fy = 0; fx = f; }
    else { int uu = f - 9; fy = 1 + uu / 17; fx = uu % 17; }
    float pyr = twc[fy], pyi = tws[fy];
    float pxr = twc[fx], pxi = tws[fx];
    int fx2 = 2 * fx; if (fx2 >= 17) fx2 -= 17;
    int fy2 = 2 * fy; if (fy2 >= 17) fy2 -= 17;
    float px2r = twc[fx2], px2i = tws[fx2];
    float py2r = twc[fy2], py2i = tws[fy2];
    float cR[9], cI[9];
    cR[0] = 1.0f;  cI[0] = 0.0f;
    cR[1] = pxr;   cI[1] = pxi;
    cR[2] = px2r;  cI[2] = px2i;
    cR[3] = pyr;   cI[3] = pyi;
    cR[4] = pyr * pxr - pyi * pxi;    cI[4] = pyr * pxi + pyi * pxr;
    cR[5] = pyr * px2r - pyi * px2i;  cI[5] = pyr * px2i + pyi * px2r;
    cR[6] = py2r;  cI[6] = py2i;
    cR[7] = py2r * pxr - py2i * pxi;  cI[7] = py2r * pxi + py2i * pxr;
    cR[8] = py2r * px2r - py2i * px2i; cI[8] = py2r * px2i + py2i * px2r;
#pragma unroll
    for (int i = 0; i < 9; ++i) { cR[i] *= XSCALE; cI[i] *= XSCALE; }  // exact 2^-10

    // ---- stage: X_f = sum_i c_i * plane_i -> swizzled LDS (4608 chunks) ----
#pragma unroll 1
    for (int j = 0; j < 6; ++j) {                 // 6 x 768 = 4608 exact
        int cidx = j * 768 + tid;
        int a = cidx / 24, c = cidx % 24;
        const float* base = Kt + a * CH + c * 8;
        float xr0 = 0.f, xr1 = 0.f, xr2 = 0.f, xr3 = 0.f;
        float xr4 = 0.f, xr5 = 0.f, xr6 = 0.f, xr7 = 0.f;
        float xi0 = 0.f, xi1 = 0.f, xi2 = 0.f, xi3 = 0.f;
        float xi4 = 0.f, xi5 = 0.f, xi6 = 0.f, xi7 = 0.f;
#pragma unroll
        for (int i = 0; i < 9; ++i) {
            f32x4 lo = *(const f32x4*)(base + (size_t)i * MAT);
            f32x4 hi = *(const f32x4*)(base + (size_t)i * MAT + 4);
            float r = cR[i], m = cI[i];
            xr0 += r * lo[0]; xi0 += m * lo[0];
            xr1 += r * lo[1]; xi1 += m * lo[1];
            xr2 += r * lo[2]; xi2 += m * lo[2];
            xr3 += r * lo[3]; xi3 += m * lo[3];
            xr4 += r * hi[0]; xi4 += m * hi[0];
            xr5 += r * hi[1]; xi5 += m * hi[1];
            xr6 += r * hi[2]; xi6 += m * hi[2];
            xr7 += r * hi[3]; xi7 += m * hi[3];
        }
        bf16x8 vr, vi;
        vr[0] = (bf16)xr0; vr[1] = (bf16)xr1; vr[2] = (bf16)xr2; vr[3] = (bf16)xr3;
        vr[4] = (bf16)xr4; vr[5] = (bf16)xr5; vr[6] = (bf16)xr6; vr[7] = (bf16)xr7;
        vi[0] = (bf16)xi0; vi[1] = (bf16)xi1; vi[2] = (bf16)xi2; vi[3] = (bf16)xi3;
        vi[4] = (bf16)xi4; vi[5] = (bf16)xi5; vi[6] = (bf16)xi6; vi[7] = (bf16)xi7;
        int e = a * CH + swz8(c, a) * 8;          // swizzled (write side)
        *(i32x4*)&lds[e]       = __builtin_bit_cast(i32x4, vr);
        *(i32x4*)&lds[MAT + e] = __builtin_bit_cast(i32x4, vi);
    }
    __syncthreads();

    f32x4 cr[3][4], ci[3][4];
#pragma unroll 1
    for (int round = 0; round < 3; ++round) {
        bool last = (round == 2);
        int Rb = last ? rb3 : rb;
        int Cb = last ? cb3 : cb;
        bool active = !last || comp3;
#pragma unroll
        for (int i = 0; i < 3; ++i)
#pragma unroll
            for (int j = 0; j < 4; ++j) {
                cr[i][j] = f32x4{0.f, 0.f, 0.f, 0.f};
                ci[i][j] = f32x4{0.f, 0.f, 0.f, 0.f};
            }
        if (active) {
#pragma unroll
            for (int ks8 = 0; ks8 < 24; ks8 += 4) {     // K step 32 = 4 chunks
                int c0 = ks8 + kqc;
                int sw = swz8(c0, mlb) * 8;             // same for all frag rows
                bf16x8 ar[3], ai[3];
#pragma unroll
                for (int mt = 0; mt < 3; ++mt) {
                    int e = (Rb + mt * 16 + ml) * CH + sw;
                    ar[mt] = *(const bf16x8*)&lds[e];
                    ai[mt] = *(const bf16x8*)&lds[MAT + e];
                }
#pragma unroll
                for (int nt = 0; nt < 4; ++nt) {
                    int e = (Cb + nt * 16 + ml) * CH + sw;
                    bf16x8 br = *(const bf16x8*)&lds[e];
                    bf16x8 bi = *(const bf16x8*)&lds[MAT + e];
                    i32x4 u = __builtin_bit_cast(i32x4, br);
                    u ^= 0x80008000;                    // nbr = -br (8 bf16)
                    bf16x8 nbr = __builtin_bit_cast(bf16x8, u);
                    // mt-major: per-accumulator order unchanged; dep dist 6
#pragma unroll
                    for (int mt = 0; mt < 3; ++mt)
                        cr[mt][nt] = __builtin_amdgcn_mfma_f32_16x16x32_bf16(ar[mt], br,  cr[mt][nt], 0, 0, 0);
#pragma unroll
                    for (int mt = 0; mt < 3; ++mt)
                        ci[mt][nt] = __builtin_amdgcn_mfma_f32_16x16x32_bf16(ar[mt], bi,  ci[mt][nt], 0, 0, 0);
#pragma unroll
                    for (int mt = 0; mt < 3; ++mt)
                        cr[mt][nt] = __builtin_amdgcn_mfma_f32_16x16x32_bf16(ai[mt], bi,  cr[mt][nt], 0, 0, 0);
#pragma unroll
                    for (int mt = 0; mt < 3; ++mt)
                        ci[mt][nt] = __builtin_amdgcn_mfma_f32_16x16x32_bf16(ai[mt], nbr, ci[mt][nt], 0, 0, 0);
                }
            }
        }
        if (!last) {
            __syncthreads();                        // all LDS reads done
            // transposed-packed write-back: store H^T (bitwise-Hermitian ->
            // transposes cancel across rounds; s3 unchanged). Lane's 4 rr
            // rows are 4 consecutive elems of stored column -> one b64.
            int lrq = kqc * 4;
#pragma unroll
            for (int mt = 0; mt < 3; ++mt) {
                int row0 = rb + mt * 16 + lrq;      // multiple of 4
                int rc = row0 >> 3, rlo = row0 & 7; // rlo in {0,4}
#pragma unroll
                for (int nt = 0; nt < 4; ++nt) {
                    int col = cb + nt * 16 + ml;
                    int e = col * CH + swz8(rc, mlb) * 8 + rlo;  // col&7 == mlb
                    bf16x4 pr, pi;
#pragma unroll
                    for (int rr = 0; rr < 4; ++rr) {
                        pr[rr] = (bf16)cr[mt][nt][rr];
                        pi[rr] = (bf16)ci[mt][nt][rr];
                    }
                    *(i32x2*)&lds[e]       = __builtin_bit_cast(i32x2, pr);
                    *(i32x2*)&lds[MAT + e] = __builtin_bit_cast(i32x2, pi);
                }
            }
            __syncthreads();                        // writes visible to round+1
        }
    }

    // ---- norm of round-3 accums: per-element weight 2/1/0 (above/diag/
    // below); active tiles cover the upper triangle exactly once ----
    float loc = 0.f;
    if (comp3) {
#pragma unroll
        for (int mt = 0; mt < 3; ++mt)
#pragma unroll
            for (int nt = 0; nt < 4; ++nt)
#pragma unroll
                for (int rr = 0; rr < 4; ++rr) {
                    int row = rb3 + mt * 16 + kqc * 4 + rr;
                    int col = cb3 + nt * 16 + ml;
                    float wt = (col > row) ? 2.0f : ((col == row) ? 1.0f : 0.0f);
                    loc += wt * (cr[mt][nt][rr] * cr[mt][nt][rr] +
                                 ci[mt][nt][rr] * ci[mt][nt][rr]);
                }
    }
#pragma unroll
    for (int off = 32; off > 0; off >>= 1) loc += __shfl_down(loc, off, 64);
    if (lane == 0) red[w] = loc;
    __syncthreads();
    if (tid == 0) {
        float base = (f == 0) ? 1.0f : 2.0f;        // conj-pair weight over freqs
        float acc = 0.f;
#pragma unroll
        for (int i = 0; i < 12; ++i) acc += red[i];
        atomicAdd(s3, base * acc);
    }
}

// sigma = 1024 * (s3/289)^(1/16);  out = K / sigma
__global__ void k_scale(const float* __restrict__ K, float* __restrict__ out,
                        const float* __restrict__ s3) {
    float sig = 1024.0f * exp2f(log2f((*s3) * (1.0f / 289.0f)) * 0.0625f);
    float inv = 1.0f / sig;
    int i = (blockIdx.x * 256 + threadIdx.x) * 4;   // 324 blocks exact
    f32x4 v = *(const f32x4*)(K + i);
    v *= inv;
    *(f32x4*)(out + i) = v;
}

extern "C" void kernel_launch(void* const* d_in, const int* in_sizes, int n_in,
                              void* d_out, int out_size, void* d_ws, size_t ws_size,
                              hipStream_t stream) {
    const float* K = (const float*)d_in[0];
    float* out = (float*)d_out;
    char* ws = (char*)d_ws;
    float* s3 = (float*)ws;
    float* Kt = (float*)(ws + 256);

    k_tr<<<NELEM / (256 * 9), 256, 0, stream>>>(K, Kt, s3);   // 9-plane Kt + s3=0
    k_g3<<<NF, 768, 0, stream>>>(Kt, s3);                     // DFT + 3 gram rounds
    k_scale<<<NELEM / 1024, 256, 0, stream>>>(K, out, s3);    // out = K/sigma
}

// Round 16
// 90.605 us; speedup vs baseline: 1.1729x; 1.0724x over previous
//
#include <hip/hip_runtime.h>
#include <hip/hip_bf16.h>

typedef __bf16 bf16;
typedef _Float16 f16;
typedef __attribute__((ext_vector_type(8))) __bf16 bf16x8;
typedef __attribute__((ext_vector_type(4))) __bf16 bf16x4;
typedef __attribute__((ext_vector_type(8))) _Float16 f16x8;
typedef __attribute__((ext_vector_type(4))) float f32x4;
typedef __attribute__((ext_vector_type(4))) int i32x4;
typedef __attribute__((ext_vector_type(2))) int i32x2;

#define CH 192
#define MAT (CH * CH)            // 36864
#define NF 145                   // canonical frequencies of 17x17 grid (conj symmetry)
#define NELEM (CH * CH * 9)      // 331776
#define XSCALE 9.765625e-4f      // 2^-10, exact; sigma = 1024*(s3/289)^(1/16)
#define W17 0.36959913571644626f // 2*pi/17

// ---------------------------------------------------------------------------
// sigma = ||G^3(K)||_F^(1/8) via 17x17 spectral sampling (exact Parseval).
// ROUND-21 CHANGE (halve staging L2 traffic): r15's 12-wave experiment
// REGRESSED (48.3 vs 43.3; VGPR=84 — compiler ignored the headroom). Wave
// sweep now monotone: 4/SIMD(43.3) > 3/SIMD(48.3) > 2/SIMD(52.9-54.2); 4 is
// the max (1024-thr block cap, LDS 147KB = 1 block/CU). Rounds REVERTED to
// the r14 16-wave structure exactly. New lever: staging is L2-BW-bound
// (1.33MB Kt f32 per block @ ~56B/cyc/CU ~= 10us of k_g3's 43.3). Kt is now
// stored F16: traffic halves (~5us). Precision: K~N(0,1), f16 rel err 2^-11
// << bf16 X-rounding 2^-8 that dominates absmax 2.441e-4 (threshold 1.02e-3,
// 4x headroom). DFT expression tree unchanged; only input rounding added.
// Lessons pinned:
//  - s_setprio around MFMA in barrier-lockstep blocks: -17% (r14). NEVER.
//  - waves/SIMD is the dominant latency-coverage knob; reg headroom is NOT
//    exploited by the compiler for pipelining (r15).
//  - ci Hermitian mirror NOT bitwise (r9). cr is. No mirrors.
//  - Per-wave reg budget = 512/(waves per SIMD); exceeding spills
//    (WRITE_SIZE is the tell).
//  - Lane-adjacent addresses must be contiguous (r7 gather +22us).
//  - XOR chunk swizzle c'=(c&~7)|((c&7)^(r&7)) BOTH sides: conflicts 2M->0.
//  - harness ws fill (~44 us) is inside the timed window: floor = 44 + work.
//  - total has +-2-3us noise independent of kernels (r14 vs r15 totals).
// ws layout: [0] float s3; [256] Kt f16 [i][a][o] 9 planes (0.66 MB).
// ---------------------------------------------------------------------------

__device__ __forceinline__ int swz8(int c, int r) {
    return (c & ~7) | ((c & 7) ^ (r & 7));       // 16-B chunk XOR swizzle
}

// Kt[i*MAT + a*CH + o] = (f16)K[(o*CH+a)*9 + i]; coalesced 36-B read per
// thread, 9 scattered 2-B writes (fire-and-forget). Also zeroes s3.
__global__ void k_tr(const float* __restrict__ K, f16* __restrict__ Kt,
                     float* __restrict__ s3) {
    int p = blockIdx.x * 256 + threadIdx.x;      // 144 blocks = 36864 rows
    if (p == 0) *s3 = 0.0f;
    int o = p / CH, a = p % CH;
    const float* src = K + (size_t)p * 9;
#pragma unroll
    for (int i = 0; i < 9; ++i)
        Kt[(size_t)i * MAT + a * CH + o] = (f16)src[i];
}

// ---------------------------------------------------------------------------
// k_g3: per-frequency fused DFT + triple gram. One block = one freq, 1024 thr.
// Staging: 9-plane coeff DFT, coalesced f16x8 plane reads (one b128 per
// plane per chunk) -> swizzled LDS (Re/Im slabs [192][192] bf16, 147456 B).
// Rounds 1-2: full 16 tiles (wave w = rows (w>>2)*48, cols (w&3)*48); MFMA
// mt-major -> barrier -> transposed-packed b64 write-back -> barrier.
// Round 3: balanced 10-tile triangle (waves 0-9), norm -> atomic.
// ---------------------------------------------------------------------------
__global__ __launch_bounds__(1024, 4)
__attribute__((amdgpu_waves_per_eu(4, 4)))
void k_g3(const f16* __restrict__ Kt, float* __restrict__ s3) {
    __shared__ __align__(16) bf16 lds[2 * MAT];   // 147456 B
    __shared__ float twc[17], tws[17];
    __shared__ float red[16];
    int f = blockIdx.x;                 // 145 blocks
    int tid = threadIdx.x;
    int lane = tid & 63, w = tid >> 6;
    int ml = lane & 15, kqc = lane >> 4;
    int mlb = ml & 7;                   // swizzle row-bit for ALL frag rows
    int rb = (w >> 2) * 48;             // rounds 1-2: full 4x4 tiling
    int cb = (w & 3) * 48;
    // round-3 balanced triangle: waves 0-9 -> (0,0)(0,1)(0,2)(0,3)(1,1)
    // (1,2)(1,3)(2,2)(2,3)(3,3); per-SIMD active = 3,3,2,2
    int tr = (w >= 4) + (w >= 7) + (w >= 9);
    int tbase = (tr == 0) ? 0 : (tr == 1) ? 4 : (tr == 2) ? 7 : 9;
    int tc = w - tbase + tr;
    bool comp3 = (w < 10);
    bool offd3 = comp3 && (tc > tr);
    int rb3 = tr * 48, cb3 = tc * 48;

    if (tid < 17) {
        float s, c;
        __sincosf(-W17 * (float)tid, &s, &c);
        twc[tid] = c; tws[tid] = s;
    }
    __syncthreads();

    // ---- 9 block-uniform complex coeffs c[y*3+x] = py^y * px^x * 2^-10 ----
    int fy, fx;
    if (f < 9) { fy = 0; fx = f; }
    else { int uu = f - 9; fy = 1 + uu / 17; fx = uu % 17; }
    float pyr = twc[fy], pyi = tws[fy];
    float pxr = twc[fx], pxi = tws[fx];
    int fx2 = 2 * fx; if (fx2 >= 17) fx2 -= 17;
    int fy2 = 2 * fy; if (fy2 >= 17) fy2 -= 17;
    float px2r = twc[fx2], px2i = tws[fx2];
    float py2r = twc[fy2], py2i = tws[fy2];
    float cR[9], cI[9];
    cR[0] = 1.0f;  cI[0] = 0.0f;
    cR[1] = pxr;   cI[1] = pxi;
    cR[2] = px2r;  cI[2] = px2i;
    cR[3] = pyr;   cI[3] = pyi;
    cR[4] = pyr * pxr - pyi * pxi;    cI[4] = pyr * pxi + pyi * pxr;
    cR[5] = pyr * px2r - pyi * px2i;  cI[5] = pyr * px2i + pyi * px2r;
    cR[6] = py2r;  cI[6] = py2i;
    cR[7] = py2r * pxr - py2i * pxi;  cI[7] = py2r * pxi + py2i * pxr;
    cR[8] = py2r * px2r - py2i * px2i; cI[8] = py2r * px2i + py2i * px2r;
#pragma unroll
    for (int i = 0; i < 9; ++i) { cR[i] *= XSCALE; cI[i] *= XSCALE; }  // exact 2^-10

    // ---- stage: X_f = sum_i c_i * plane_i -> swizzled LDS (4608 chunks) ----
#pragma unroll 1
    for (int j5 = 0; j5 < 5; ++j5) {
        int cidx = j5 * 1024 + tid;
        if (cidx < 4608) {                        // last pass: waves 0-7 only
            int a = cidx / 24, c = cidx % 24;
            const f16* base = Kt + a * CH + c * 8;
            float xr0 = 0.f, xr1 = 0.f, xr2 = 0.f, xr3 = 0.f;
            float xr4 = 0.f, xr5 = 0.f, xr6 = 0.f, xr7 = 0.f;
            float xi0 = 0.f, xi1 = 0.f, xi2 = 0.f, xi3 = 0.f;
            float xi4 = 0.f, xi5 = 0.f, xi6 = 0.f, xi7 = 0.f;
#pragma unroll
            for (int i = 0; i < 9; ++i) {
                f16x8 hv = *(const f16x8*)(base + (size_t)i * MAT);  // one b128
                float r = cR[i], m = cI[i];
                float v0 = (float)hv[0], v1 = (float)hv[1];
                float v2 = (float)hv[2], v3 = (float)hv[3];
                float v4 = (float)hv[4], v5 = (float)hv[5];
                float v6 = (float)hv[6], v7 = (float)hv[7];
                xr0 += r * v0; xi0 += m * v0;
                xr1 += r * v1; xi1 += m * v1;
                xr2 += r * v2; xi2 += m * v2;
                xr3 += r * v3; xi3 += m * v3;
                xr4 += r * v4; xi4 += m * v4;
                xr5 += r * v5; xi5 += m * v5;
                xr6 += r * v6; xi6 += m * v6;
                xr7 += r * v7; xi7 += m * v7;
            }
            bf16x8 vr, vi;
            vr[0] = (bf16)xr0; vr[1] = (bf16)xr1; vr[2] = (bf16)xr2; vr[3] = (bf16)xr3;
            vr[4] = (bf16)xr4; vr[5] = (bf16)xr5; vr[6] = (bf16)xr6; vr[7] = (bf16)xr7;
            vi[0] = (bf16)xi0; vi[1] = (bf16)xi1; vi[2] = (bf16)xi2; vi[3] = (bf16)xi3;
            vi[4] = (bf16)xi4; vi[5] = (bf16)xi5; vi[6] = (bf16)xi6; vi[7] = (bf16)xi7;
            int e = a * CH + swz8(c, a) * 8;      // swizzled (write side)
            *(i32x4*)&lds[e]       = __builtin_bit_cast(i32x4, vr);
            *(i32x4*)&lds[MAT + e] = __builtin_bit_cast(i32x4, vi);
        }
    }
    __syncthreads();

    f32x4 cr[3][3], ci[3][3];
#pragma unroll 1
    for (int round = 0; round < 3; ++round) {
        bool last = (round == 2);
        int Rb = last ? rb3 : rb;
        int Cb = last ? cb3 : cb;
        bool active = !last || comp3;
#pragma unroll
        for (int i = 0; i < 3; ++i)
#pragma unroll
            for (int j = 0; j < 3; ++j) {
                cr[i][j] = f32x4{0.f, 0.f, 0.f, 0.f};
                ci[i][j] = f32x4{0.f, 0.f, 0.f, 0.f};
            }
        if (active) {
#pragma unroll
            for (int ks8 = 0; ks8 < 24; ks8 += 4) {     // K step 32 = 4 chunks
                int c0 = ks8 + kqc;
                int sw = swz8(c0, mlb) * 8;             // same for all frag rows
                bf16x8 ar[3], ai[3];
#pragma unroll
                for (int mt = 0; mt < 3; ++mt) {
                    int e = (Rb + mt * 16 + ml) * CH + sw;
                    ar[mt] = *(const bf16x8*)&lds[e];
                    ai[mt] = *(const bf16x8*)&lds[MAT + e];
                }
#pragma unroll
                for (int nt = 0; nt < 3; ++nt) {
                    int e = (Cb + nt * 16 + ml) * CH + sw;
                    bf16x8 br = *(const bf16x8*)&lds[e];
                    bf16x8 bi = *(const bf16x8*)&lds[MAT + e];
                    i32x4 u = __builtin_bit_cast(i32x4, br);
                    u ^= 0x80008000;                    // nbr = -br (8 bf16)
                    bf16x8 nbr = __builtin_bit_cast(bf16x8, u);
                    // mt-major: per-accumulator order unchanged; dep dist 6
#pragma unroll
                    for (int mt = 0; mt < 3; ++mt)
                        cr[mt][nt] = __builtin_amdgcn_mfma_f32_16x16x32_bf16(ar[mt], br,  cr[mt][nt], 0, 0, 0);
#pragma unroll
                    for (int mt = 0; mt < 3; ++mt)
                        ci[mt][nt] = __builtin_amdgcn_mfma_f32_16x16x32_bf16(ar[mt], bi,  ci[mt][nt], 0, 0, 0);
#pragma unroll
                    for (int mt = 0; mt < 3; ++mt)
                        cr[mt][nt] = __builtin_amdgcn_mfma_f32_16x16x32_bf16(ai[mt], bi,  cr[mt][nt], 0, 0, 0);
#pragma unroll
                    for (int mt = 0; mt < 3; ++mt)
                        ci[mt][nt] = __builtin_amdgcn_mfma_f32_16x16x32_bf16(ai[mt], nbr, ci[mt][nt], 0, 0, 0);
                }
            }
        }
        if (!last) {
            __syncthreads();                        // all LDS reads done
            // transposed-packed write-back: store H^T (bitwise-Hermitian ->
            // transposes cancel across rounds; s3 unchanged). Lane's 4 rr
            // rows are 4 consecutive elems of stored column -> one b64.
            int lrq = kqc * 4;
#pragma unroll
            for (int mt = 0; mt < 3; ++mt) {
                int row0 = rb + mt * 16 + lrq;      // multiple of 4
                int rc = row0 >> 3, rlo = row0 & 7; // rlo in {0,4}
#pragma unroll
                for (int nt = 0; nt < 3; ++nt) {
                    int col = cb + nt * 16 + ml;
                    int e = col * CH + swz8(rc, mlb) * 8 + rlo;  // col&7 == mlb
                    bf16x4 pr, pi;
#pragma unroll
                    for (int rr = 0; rr < 4; ++rr) {
                        pr[rr] = (bf16)cr[mt][nt][rr];
                        pi[rr] = (bf16)ci[mt][nt][rr];
                    }
                    *(i32x2*)&lds[e]       = __builtin_bit_cast(i32x2, pr);
                    *(i32x2*)&lds[MAT + e] = __builtin_bit_cast(i32x2, pi);
                }
            }
            __syncthreads();                        // writes visible to round+1
        }
    }

    // ---- norm of round-3 accums: triangle, diag w=1, off-diag w=2 ----
    float loc = 0.f;
#pragma unroll
    for (int mt = 0; mt < 3; ++mt)
#pragma unroll
        for (int nt = 0; nt < 3; ++nt)
#pragma unroll
            for (int rr = 0; rr < 4; ++rr)
                loc += cr[mt][nt][rr] * cr[mt][nt][rr] + ci[mt][nt][rr] * ci[mt][nt][rr];
    loc *= offd3 ? 2.0f : (comp3 ? 1.0f : 0.0f);
#pragma unroll
    for (int off = 32; off > 0; off >>= 1) loc += __shfl_down(loc, off, 64);
    if (lane == 0) red[w] = loc;
    __syncthreads();
    if (tid == 0) {
        float base = (f == 0) ? 1.0f : 2.0f;        // conj-pair weight over freqs
        float acc = 0.f;
#pragma unroll
        for (int i = 0; i < 16; ++i) acc += red[i];
        atomicAdd(s3, base * acc);
    }
}

// sigma = 1024 * (s3/289)^(1/16);  out = K / sigma
__global__ void k_scale(const float* __restrict__ K, float* __restrict__ out,
                        const float* __restrict__ s3) {
    float sig = 1024.0f * exp2f(log2f((*s3) * (1.0f / 289.0f)) * 0.0625f);
    float inv = 1.0f / sig;
    int i = (blockIdx.x * 256 + threadIdx.x) * 4;   // 324 blocks exact
    f32x4 v = *(const f32x4*)(K + i);
    v *= inv;
    *(f32x4*)(out + i) = v;
}

extern "C" void kernel_launch(void* const* d_in, const int* in_sizes, int n_in,
                              void* d_out, int out_size, void* d_ws, size_t ws_size,
                              hipStream_t stream) {
    const float* K = (const float*)d_in[0];
    float* out = (float*)d_out;
    char* ws = (char*)d_ws;
    float* s3 = (float*)ws;
    f16* Kt = (f16*)(ws + 256);

    k_tr<<<NELEM / (256 * 9), 256, 0, stream>>>(K, Kt, s3);   // f16 Kt + s3=0
    k_g3<<<NF, 1024, 0, stream>>>(Kt, s3);                    // DFT + 3 gram rounds
    k_scale<<<NELEM / 1024, 256, 0, stream>>>(K, out, s3);    // out = K/sigma
}